// Round 2
// baseline (176.483 us; speedup 1.0000x reference)
//
#include <hip/hip_runtime.h>
#include <hip/hip_bf16.h>
#include <stdint.h>

typedef float  f32x4  __attribute__((ext_vector_type(4)));
typedef __bf16 bf16x8 __attribute__((ext_vector_type(8)));
typedef unsigned short us4 __attribute__((ext_vector_type(4)));

#define NDIM 4096
#define DDIM 512
#define PSTRIDE 2097152   // elements per split-K partial (512*4096 = 4096*512)
#define NPART 8           // split-K factor for the two big GEMMs (256 blocks = 1/CU)

__device__ __forceinline__ unsigned short f2bf(float f) {
    union { float f; uint32_t u; } v; v.f = f;
    uint32_t u = v.u;
    u += 0x7FFFu + ((u >> 16) & 1u);   // round-to-nearest-even
    return (unsigned short)(u >> 16);
}

__device__ __forceinline__ float b2f(unsigned short s) {
    union { uint32_t u; float f; } v; v.u = (uint32_t)s << 16; return v.f;
}

__device__ __forceinline__ f32x4 us4tof(us4 u) {
    f32x4 r; r.x = b2f(u.x); r.y = b2f(u.y); r.z = b2f(u.z); r.w = b2f(u.w);
    return r;
}

// Fused prep (block-range dispatch):
//   [0, 16384)      : A fp32 -> bf16 with +I      (4096x4096, float4/thread)
//   [16384, 18432)  : X fp32 -> bf16              (4096x512)
//   [18432, 18688)  : W fp32 -> bf16              (512x512)
//   [18688, 18704)  : ds[i] = rsqrt(A[i,i]+1)
__global__ void prep_kernel(const float* __restrict__ A, const float* __restrict__ X,
                            const float* __restrict__ W,
                            unsigned short* __restrict__ A2, unsigned short* __restrict__ Xb,
                            unsigned short* __restrict__ Wb, float* __restrict__ ds) {
    const int b = blockIdx.x, tid = threadIdx.x;
    if (b < 16384) {
        int i = b * 256 + tid;          // float4 index into A
        int e = i << 2;
        int row = e >> 12, col = e & 4095;
        f32x4 v = ((const f32x4*)A)[i];
        int d = row - col;
        if (d >= 0 && d < 4) v[d] += 1.0f;
        us4 o; o.x = f2bf(v.x); o.y = f2bf(v.y); o.z = f2bf(v.z); o.w = f2bf(v.w);
        ((us4*)A2)[i] = o;
    } else if (b < 18432) {
        int i = (b - 16384) * 256 + tid;
        f32x4 v = ((const f32x4*)X)[i];
        us4 o; o.x = f2bf(v.x); o.y = f2bf(v.y); o.z = f2bf(v.z); o.w = f2bf(v.w);
        ((us4*)Xb)[i] = o;
    } else if (b < 18688) {
        int i = (b - 18432) * 256 + tid;
        f32x4 v = ((const f32x4*)W)[i];
        us4 o; o.x = f2bf(v.x); o.y = f2bf(v.y); o.z = f2bf(v.z); o.w = f2bf(v.w);
        ((us4*)Wb)[i] = o;
    } else {
        int i = (b - 18688) * 256 + tid;
        if (i < NDIM) ds[i] = rsqrtf(A[(size_t)i * (NDIM + 1)] + 1.0f);
    }
}

// ---------------------------------------------------------------------------
// Small GEMM (proven path), used only for Yt = (X@W^T)^T.
// C = A @ B^T.  128x128 tile, BK=128, MODE 0: store bf16 TRANSPOSED.
// ---------------------------------------------------------------------------
template <int MODE, int SWAP>
__global__ __launch_bounds__(256, 2) void gemm_bt(
    const unsigned short* __restrict__ A,
    const unsigned short* __restrict__ B,
    void* __restrict__ C,
    int K, int kc, int ldc)
{
    __shared__ unsigned short lsA[128 * 128];
    __shared__ unsigned short lsB[128 * 128];

    const int tid  = threadIdx.x;
    const int wid  = tid >> 6;
    const int lane = tid & 63;
    const int m0 = (SWAP ? blockIdx.y : blockIdx.x) * 128;
    const int n0 = (SWAP ? blockIdx.x : blockIdx.y) * 128;
    const int kbase = blockIdx.z * kc;
    const int wm = (wid & 1) * 64;
    const int wn = (wid >> 1) * 64;
    const int quad = lane >> 4;
    const int c16  = lane & 15;

    const int lr    = lane >> 4;        // row within instr (0..3)
    const int chunk = lane & 15;        // 16B chunk within row
    const int offe = ((chunk ^ lr) * 16);

    f32x4 acc[4][4];
    #pragma unroll
    for (int i = 0; i < 4; i++)
        #pragma unroll
        for (int j = 0; j < 4; j++) acc[i][j] = (f32x4)0.0f;

    const char* gA = (const char*)A + ((size_t)(m0 + wid * 32 + lr) * K) * 2;
    const char* gB = (const char*)B + ((size_t)(n0 + wid * 32 + lr) * K) * 2;
    const size_t rowstep = (size_t)4 * K * 2;

    for (int k0 = kbase; k0 < kbase + kc; k0 += 128) {
        const size_t kb = (size_t)k0 * 2;
        #pragma unroll
        for (int i = 0; i < 8; i++) {
            const size_t src = kb + (size_t)i * rowstep + (size_t)(offe ^ ((i & 1) << 6));
            __builtin_amdgcn_global_load_lds(
                (const __attribute__((address_space(1))) void*)(gA + src),
                (__attribute__((address_space(3))) void*)(&lsA[(wid * 8 + i) * 512]),
                16, 0, 0);
            __builtin_amdgcn_global_load_lds(
                (const __attribute__((address_space(1))) void*)(gB + src),
                (__attribute__((address_space(3))) void*)(&lsB[(wid * 8 + i) * 512]),
                16, 0, 0);
        }
        __syncthreads();

        #pragma unroll
        for (int ks = 0; ks < 4; ks++) {
            bf16x8 bfrag[4], afrag[4];
            #pragma unroll
            for (int nt = 0; nt < 4; nt++) {
                int r = wn + nt * 16 + c16;
                int pc = (quad + ks * 4) ^ (r & 7);
                bfrag[nt] = *(const bf16x8*)((const char*)lsB + r * 256 + pc * 16);
            }
            #pragma unroll
            for (int mt = 0; mt < 4; mt++) {
                int r = wm + mt * 16 + c16;
                int pc = (quad + ks * 4) ^ (r & 7);
                afrag[mt] = *(const bf16x8*)((const char*)lsA + r * 256 + pc * 16);
            }
            #pragma unroll
            for (int mt = 0; mt < 4; mt++)
                #pragma unroll
                for (int nt = 0; nt < 4; nt++)
                    acc[mt][nt] = __builtin_amdgcn_mfma_f32_16x16x32_bf16(
                        afrag[mt], bfrag[nt], acc[mt][nt], 0, 0, 0);
        }
        __syncthreads();
    }

    #pragma unroll
    for (int mt = 0; mt < 4; mt++) {
        const int gm0 = m0 + wm + mt * 16 + quad * 4;
        #pragma unroll
        for (int nt = 0; nt < 4; nt++) {
            const int gn = n0 + wn + nt * 16 + c16;
            f32x4 v = acc[mt][nt];
            if (MODE == 0) {
                us4 o;
                o.x = f2bf(v.x); o.y = f2bf(v.y); o.z = f2bf(v.z); o.w = f2bf(v.w);
                *(us4*)((unsigned short*)C + (size_t)gn * ldc + gm0) = o;
            } else {
                unsigned short* o = (unsigned short*)C + (size_t)blockIdx.z * PSTRIDE
                                  + (size_t)gm0 * ldc + gn;
                o[0]               = f2bf(v.x);
                o[ldc]             = f2bf(v.y);
                o[2 * (size_t)ldc] = f2bf(v.z);
                o[3 * (size_t)ldc] = f2bf(v.w);
            }
        }
    }
}

// ---------------------------------------------------------------------------
// 256x256 8-phase GEMM (T2+T3+T4+T5).  C = A @ B^T, bf16 in, bf16 split-K
// partials out (C + z*PSTRIDE, row-major [M x ldc]).
//   BM=BN=256, BK=64, 512 threads = 8 waves (2M x 4N), wave tile 128x64.
//   LDS 128 KB: [buf 0/1][A 256x64 | B 256x64] bf16, XOR-(r&7) swizzle at
//   16B chunks (both-sides: pre-swizzled global_load_lds source + swizzled
//   ds_read).  4 phases per K-tile; phase p computes mt={2p,2p+1} x nt=0..3
//   x ks=0,1 (16 MFMA).  Staging for tile t+1 issued 2 loads/phase during
//   tile t in order B0,B1,B2,B3,A0,A1,A2,A3; A-instr p stages exactly the
//   rows phase p consumes, so counted waits vmcnt(3,4,5,6) gate each phase
//   without ever draining the queue (steady state: 8 loads in flight).
//   Ledger: prologue 8 -> wait3(+2) 5 -> wait4(+2) 6 -> wait5(+2) 7 ->
//   wait6(+2) 8 -> next tile wait3 ...; drain 3,2,1,0 on final tile.
// ---------------------------------------------------------------------------
#define VMW(n)  asm volatile("s_waitcnt vmcnt(" #n ")" ::: "memory")
#define LGKM0   asm volatile("s_waitcnt lgkmcnt(0)" ::: "memory")
#define SBAR    __builtin_amdgcn_s_barrier()
#define SCH0    __builtin_amdgcn_sched_barrier(0)
#define GLB(src, dst) __builtin_amdgcn_global_load_lds( \
    (const __attribute__((address_space(1))) void*)(src), \
    (__attribute__((address_space(3))) void*)(dst), 16, 0, 0)
#define DSR(off) (*(const bf16x8*)(ldsc + (off)))

// One phase. p, vm are literals; STMT = staging statements (may be empty).
#define PHASE(p, vm, STMT) do {                                               \
    VMW(vm); SBAR; SCH0;                                                      \
    bf16x8 a00 = DSR(bo + baseA0 + (2*(p))*2048);                             \
    bf16x8 a01 = DSR(bo + baseA1 + (2*(p))*2048);                             \
    bf16x8 a10 = DSR(bo + baseA0 + (2*(p)+1)*2048);                           \
    bf16x8 a11 = DSR(bo + baseA1 + (2*(p)+1)*2048);                           \
    if ((p) == 0) {                                                           \
        _Pragma("unroll")                                                     \
        for (int nt = 0; nt < 4; nt++) {                                      \
            fb0[nt] = DSR(bo + baseB0 + nt*2048);                             \
            fb1[nt] = DSR(bo + baseB1 + nt*2048);                             \
        }                                                                     \
    }                                                                         \
    STMT                                                                      \
    LGKM0; SCH0;                                                              \
    __builtin_amdgcn_s_setprio(1);                                            \
    _Pragma("unroll")                                                         \
    for (int nt = 0; nt < 4; nt++) {                                          \
        acc[2*(p)][nt]   = __builtin_amdgcn_mfma_f32_16x16x32_bf16(a00, fb0[nt], acc[2*(p)][nt], 0, 0, 0);   \
        acc[2*(p)][nt]   = __builtin_amdgcn_mfma_f32_16x16x32_bf16(a01, fb1[nt], acc[2*(p)][nt], 0, 0, 0);   \
        acc[2*(p)+1][nt] = __builtin_amdgcn_mfma_f32_16x16x32_bf16(a10, fb0[nt], acc[2*(p)+1][nt], 0, 0, 0); \
        acc[2*(p)+1][nt] = __builtin_amdgcn_mfma_f32_16x16x32_bf16(a11, fb1[nt], acc[2*(p)+1][nt], 0, 0, 0); \
    }                                                                         \
    __builtin_amdgcn_s_setprio(0);                                            \
} while (0)

template <int SWAP>
__global__ __launch_bounds__(512, 2) void gemm256_bt(
    const unsigned short* __restrict__ A,
    const unsigned short* __restrict__ B,
    unsigned short* __restrict__ C,
    int K, int kc, int ldc)
{
    __shared__ unsigned short lds[65536];   // 128 KB

    const int tid  = threadIdx.x;
    const int wid  = tid >> 6;               // 0..7
    const int lane = tid & 63;
    const int m0 = (SWAP ? blockIdx.y : blockIdx.x) * 256;
    const int n0 = (SWAP ? blockIdx.x : blockIdx.y) * 256;
    const int kbase = blockIdx.z * kc;

    const int wm = (wid >> 2) * 128;         // 0 or 128
    const int wn = (wid & 3) * 64;           // 0,64,128,192
    const int quad = lane >> 4;
    const int c16  = lane & 15;
    const int keyq = c16 & 7;

    const char* ldsc = (const char*)lds;

    // fragment LDS byte bases within a buffer (row r -> chunk (ks*4+quad)^(r&7))
    const int baseA0 = (wm + c16) * 128 + ((quad ^ keyq) * 16);
    const int baseA1 = baseA0 ^ 64;                        // ks=1 flips chunk bit2
    const int baseB0 = 32768 + (wn + c16) * 128 + ((quad ^ keyq) * 16);
    const int baseB1 = baseB0 ^ 64;

    // staging geometry: each global_load_lds covers 8 rows (8 lanes x 16B/row);
    // lane l -> row lr3 = l>>3, phys chunk ch8 = l&7; source pre-swizzled so
    // phys chunk p of row r holds logical chunk p^(r&7)  (r&7 == lr3).
    const int lr3 = lane >> 3, ch8 = lane & 7;
    const int srcx = ((ch8 ^ lr3) << 4);
    // A instr i covers tile rows 32i + (wid&3)*8 + (wid>>2)*128 + lr3
    const char* gA = (const char*)A
        + ((size_t)(m0 + (wid & 3) * 8 + (wid >> 2) * 128 + lr3) * K + kbase) * 2 + srcx;
    // B instr j covers tile rows 64j + wid*8 + lr3
    const char* gB = (const char*)B
        + ((size_t)(n0 + wid * 8 + lr3) * K + kbase) * 2 + srcx;
    const size_t stepA = (size_t)32 * K * 2;
    const size_t stepB = (size_t)64 * K * 2;

    // wave-uniform LDS staging dests (short index, buf0)
    const int dAo = (wid & 3) * 512 + (wid >> 2) * 8192;   // A: (wid&3)*1024B + (wid>>2)*16KB
    const int dBo = 16384 + wid * 512;                     // B: 32KB + wid*1024B

    f32x4 acc[8][4];
    #pragma unroll
    for (int i = 0; i < 8; i++)
        #pragma unroll
        for (int j = 0; j < 4; j++) acc[i][j] = (f32x4)0.0f;

    const int T = kc >> 6;   // K-tiles of 64

    // prologue: stage tile 0 into buf0, order B0..B3, A0..A3
    #pragma unroll
    for (int j = 0; j < 4; j++) GLB(gB + (size_t)j * stepB, &lds[dBo + j * 4096]);
    #pragma unroll
    for (int i = 0; i < 4; i++) GLB(gA + (size_t)i * stepA, &lds[dAo + i * 2048]);

    int bo = 0;   // byte offset of compute buffer (0 / 65536)
    for (int kt = 0; kt < T - 1; ++kt) {
        const char* sA = gA + (size_t)(kt + 1) * 128;
        const char* sB = gB + (size_t)(kt + 1) * 128;
        const int sb = (bo ^ 65536) >> 1;    // stage buffer short base
        bf16x8 fb0[4], fb1[4];
        PHASE(0, 3, { GLB(sB,                     &lds[sb + dBo]);
                      GLB(sB + stepB,             &lds[sb + dBo + 4096]); });
        PHASE(1, 4, { GLB(sB + 2 * stepB,         &lds[sb + dBo + 8192]);
                      GLB(sB + 3 * stepB,         &lds[sb + dBo + 12288]); });
        PHASE(2, 5, { GLB(sA,                     &lds[sb + dAo]);
                      GLB(sA + stepA,             &lds[sb + dAo + 2048]); });
        PHASE(3, 6, { GLB(sA + 2 * stepA,         &lds[sb + dAo + 4096]);
                      GLB(sA + 3 * stepA,         &lds[sb + dAo + 6144]); });
        bo ^= 65536;
    }
    {   // final tile: no staging; drain with counted waits
        bf16x8 fb0[4], fb1[4];
        PHASE(0, 3, );
        PHASE(1, 2, );
        PHASE(2, 1, );
        PHASE(3, 0, );
    }

    // epilogue: C/D layout col = lane&15, row = quad*4 + reg
    unsigned short* Cp = C + (size_t)blockIdx.z * PSTRIDE;
    #pragma unroll
    for (int mt = 0; mt < 8; mt++) {
        const int gm0 = m0 + wm + mt * 16 + quad * 4;
        #pragma unroll
        for (int nt = 0; nt < 4; nt++) {
            const int gn = n0 + wn + nt * 16 + c16;
            f32x4 v = acc[mt][nt];
            unsigned short* o = Cp + (size_t)gm0 * ldc + gn;
            o[0]               = f2bf(v.x);
            o[ldc]             = f2bf(v.y);
            o[2 * (size_t)ldc] = f2bf(v.z);
            o[3 * (size_t)ldc] = f2bf(v.w);
        }
    }
}

// T2[j][i] = bf16(ds[i] * sum_z P[z][j][i]).  P: NPART bf16 partials [512 x 4096].
__global__ void ep2_kernel(const unsigned short* __restrict__ P, const float* __restrict__ ds,
                           unsigned short* __restrict__ T2) {
    int t = blockIdx.x * 256 + threadIdx.x;
    int e = t << 2;
    int i = e & 4095;                  // column index
    f32x4 v = us4tof(((const us4*)P)[t]);
    #pragma unroll
    for (int z = 1; z < NPART; z++)
        v += us4tof(((const us4*)(P + (size_t)z * PSTRIDE))[t]);
    f32x4 d = *(const f32x4*)(ds + i);
    us4 o;
    o.x = f2bf(v.x * d.x); o.y = f2bf(v.y * d.y);
    o.z = f2bf(v.z * d.z); o.w = f2bf(v.w * d.w);
    ((us4*)T2)[t] = o;
}

// out[i][j] = relu(ds[i] * sum_z Q[z][i][j]).  Q: NPART bf16 partials [4096 x 512].
__global__ void ep3_kernel(const unsigned short* __restrict__ Q, const float* __restrict__ ds,
                           float* __restrict__ out) {
    int t = blockIdx.x * 256 + threadIdx.x;
    int e = t << 2;
    int i = e >> 9;                    // row index
    float s = ds[i];
    f32x4 v = us4tof(((const us4*)Q)[t]);
    #pragma unroll
    for (int z = 1; z < NPART; z++)
        v += us4tof(((const us4*)(Q + (size_t)z * PSTRIDE))[t]);
    f32x4 o;
    o.x = fmaxf(v.x * s, 0.0f); o.y = fmaxf(v.y * s, 0.0f);
    o.z = fmaxf(v.z * s, 0.0f); o.w = fmaxf(v.w * s, 0.0f);
    ((f32x4*)out)[t] = o;
}

extern "C" void kernel_launch(void* const* d_in, const int* in_sizes, int n_in,
                              void* d_out, int out_size, void* d_ws, size_t ws_size,
                              hipStream_t stream) {
    const float* X = (const float*)d_in[0];   // [4096 x 512]
    const float* A = (const float*)d_in[1];   // [4096 x 4096]
    const float* W = (const float*)d_in[2];   // [512 x 512]

    char* ws = (char*)d_ws;
    float*          dsc  = (float*)ws;                           // 16 KB
    unsigned short* A2   = (unsigned short*)(ws + 16384);        // 32 MB   bf16 A+I
    unsigned short* Xb   = (unsigned short*)(ws + 33570816u);    // 4 MB
    unsigned short* Wb   = (unsigned short*)(ws + 37765120u);    // 512 KB
    unsigned short* Yt   = (unsigned short*)(ws + 38289408u);    // 4 MB    (X@W^T)^T  [512][4096]
    unsigned short* T2   = (unsigned short*)(ws + 42483712u);    // 4 MB    ds*(A2@Y) transposed [512][4096]
    unsigned short* Part = (unsigned short*)(ws + 46678016u);    // 32 MB   NPART x bf16 split-K partials

    prep_kernel<<<18704, 256, 0, stream>>>(A, X, W, A2, Xb, Wb, dsc);

    // Yt = (Xb @ Wb^T)^T  [512][4096] bf16 (small GEMM, 128^2 path).
    gemm_bt<0, 0><<<dim3(32, 4, 1), 256, 0, stream>>>(Xb, Wb, Yt, 512, 512, 4096);
    // Part[z][512][4096] = Yt @ A2^T partials.  M=512 (2 y-tiles), N=4096 (16 x-tiles), z=8.
    gemm256_bt<1><<<dim3(16, 2, NPART), 512, 0, stream>>>(Yt, A2, Part, 4096, 4096 / NPART, 4096);
    // T2 = bf16(ds_col * sum_z Part[z]).
    ep2_kernel<<<2048, 256, 0, stream>>>(Part, dsc, T2);
    // Part[z][4096][512] = A2 @ T2^T partials.  M=4096 (16 x-tiles), N=512 (2 y-tiles), z=8.
    gemm256_bt<0><<<dim3(16, 2, NPART), 512, 0, stream>>>(A2, T2, Part, 4096, 4096 / NPART, 512);
    // out = relu(ds_row * sum_z Part[z])  [4096 x 512] fp32.
    ep3_kernel<<<2048, 256, 0, stream>>>(Part, dsc, (float*)d_out);
}